// Round 1
// baseline (574.042 us; speedup 1.0000x reference)
//
#include <hip/hip_runtime.h>

#define DEV __device__ __forceinline__

typedef __attribute__((ext_vector_type(4))) float f32x4;
typedef __attribute__((ext_vector_type(8))) short s16x8;
typedef __attribute__((ext_vector_type(8))) __bf16 bf16x8;

static constexpr int D_MODEL = 1024;
static constexpr int SEQ = 2048;
static constexpr int NB = 4;
static constexpr int NH = 16;
static constexpr float LOG2E = 1.442695040888963f;

DEV unsigned short f2bf(float f) {
  unsigned int u = __builtin_bit_cast(unsigned int, f);
  u += 0x7fffu + ((u >> 16) & 1u);
  return (unsigned short)(u >> 16);
}

DEV s16x8 pack8(f32x4 a, f32x4 b) {
  s16x8 r;
  r[0] = (short)f2bf(a[0]); r[1] = (short)f2bf(a[1]);
  r[2] = (short)f2bf(a[2]); r[3] = (short)f2bf(a[3]);
  r[4] = (short)f2bf(b[0]); r[5] = (short)f2bf(b[1]);
  r[6] = (short)f2bf(b[2]); r[7] = (short)f2bf(b[3]);
  return r;
}

DEV f32x4 MFMA(s16x8 a, s16x8 b, f32x4 c) {
  return __builtin_amdgcn_mfma_f32_16x16x32_bf16(
      __builtin_bit_cast(bf16x8, a), __builtin_bit_cast(bf16x8, b), c, 0, 0, 0);
}

// C[m,n] = sum_k A[m,k] * W[n,k] + bias[n]
// AMODE 0: A fp32; AMODE 1: A bf16
// OUT_MODE 0: q bf16 [BH][S][64] scaled by 0.125
// OUT_MODE 1: k bf16 [BH][S][64]
// OUT_MODE 2: vT bf16 [BH][64][S]
// OUT_MODE 3: fp32 [M][1024]
template <int AMODE, int OUT_MODE>
__global__ __launch_bounds__(256) void gemm_bt(const void* __restrict__ Ap,
                                               const float* __restrict__ Wp,
                                               const float* __restrict__ bias,
                                               void* __restrict__ outp) {
  constexpr int K = 1024;
  constexpr int BK = 64;
  __shared__ __align__(16) unsigned char ldsA[2][128 * BK * 2];
  __shared__ __align__(16) unsigned char ldsB[2][128 * BK * 2];

  const int tid = threadIdx.x;
  const int wid = tid >> 6, lane = tid & 63;
  const int g16 = lane >> 4, l16 = lane & 15;
  const int m0 = blockIdx.y * 128;
  const int n0 = blockIdx.x * 128;
  const int wm = (wid >> 1) * 64, wn = (wid & 1) * 64;

  f32x4 acc[4][4];
#pragma unroll
  for (int a = 0; a < 4; ++a)
#pragma unroll
    for (int b = 0; b < 4; ++b) acc[a][b] = f32x4{0.f, 0.f, 0.f, 0.f};

  auto stage = [&](int buf, int kt) {
    const int k0 = kt * BK;
#pragma unroll
    for (int j = 0; j < 4; ++j) {
      const int cid = j * 256 + tid;  // 0..1023 chunk of 16B in 128x64 bf16 tile
      const int r = cid >> 3;
      const int c = (cid & 7) * 8;
      const int dst = (cid * 16) ^ ((r & 7) << 4);
      s16x8 av;
      if constexpr (AMODE == 0) {
        const float* s = (const float*)Ap + (size_t)(m0 + r) * K + k0 + c;
        av = pack8(*(const f32x4*)s, *(const f32x4*)(s + 4));
      } else {
        av = *(const s16x8*)((const unsigned short*)Ap + (size_t)(m0 + r) * K + k0 + c);
      }
      *(s16x8*)(ldsA[buf] + dst) = av;
      const float* ws = Wp + (size_t)(n0 + r) * K + k0 + c;
      *(s16x8*)(ldsB[buf] + dst) = pack8(*(const f32x4*)ws, *(const f32x4*)(ws + 4));
    }
  };

  auto compute = [&](int buf) {
#pragma unroll
    for (int ks = 0; ks < 2; ++ks) {
      const int kb2 = (ks * 32 + g16 * 8) * 2;
      s16x8 af[4], bfr[4];
#pragma unroll
      for (int mf = 0; mf < 4; ++mf) {
        const int row = wm + mf * 16 + l16;
        af[mf] = *(const s16x8*)(ldsA[buf] + ((row * 128 + kb2) ^ ((row & 7) << 4)));
      }
#pragma unroll
      for (int nf = 0; nf < 4; ++nf) {
        const int row = wn + nf * 16 + l16;
        bfr[nf] = *(const s16x8*)(ldsB[buf] + ((row * 128 + kb2) ^ ((row & 7) << 4)));
      }
#pragma unroll
      for (int mf = 0; mf < 4; ++mf)
#pragma unroll
        for (int nf = 0; nf < 4; ++nf)
          acc[mf][nf] = MFMA(af[mf], bfr[nf], acc[mf][nf]);
    }
  };

  stage(0, 0);
  __syncthreads();
  int buf = 0;
#pragma unroll 1
  for (int kt = 0; kt < K / BK; ++kt) {
    if (kt + 1 < K / BK) stage(buf ^ 1, kt + 1);
    compute(buf);
    __syncthreads();
    buf ^= 1;
  }

#pragma unroll
  for (int nf = 0; nf < 4; ++nf) {
    const int n = n0 + wn + nf * 16 + l16;
    const float bv = bias[n];
#pragma unroll
    for (int mf = 0; mf < 4; ++mf) {
#pragma unroll
      for (int i = 0; i < 4; ++i) {
        const int m = m0 + wm + mf * 16 + g16 * 4 + i;
        float v = acc[mf][nf][i] + bv;
        if constexpr (OUT_MODE == 0 || OUT_MODE == 1) {
          if constexpr (OUT_MODE == 0) v *= 0.125f;  // 1/sqrt(Dk)
          const int bh = (m >> 11) * NH + (n >> 6);
          ((unsigned short*)outp)[((size_t)bh * SEQ + (m & 2047)) * 64 + (n & 63)] =
              f2bf(v);
        } else if constexpr (OUT_MODE == 2) {
          const int bh = (m >> 11) * NH + (n >> 6);
          ((unsigned short*)outp)[((size_t)bh * 64 + (n & 63)) * SEQ + (m & 2047)] =
              f2bf(v);
        } else {
          ((float*)outp)[(size_t)m * D_MODEL + n] = v;
        }
      }
    }
  }
}

// Causal flash attention. grid (S/64, B*H). 4 waves, each owns 16 q rows.
// q,k: [BH][S][64] bf16 (q pre-scaled). vT: [BH][64][S] bf16.
// ctx out: [B*S][1024] bf16.
__global__ __launch_bounds__(256) void attn_kernel(
    const unsigned short* __restrict__ q, const unsigned short* __restrict__ k,
    const unsigned short* __restrict__ vT, unsigned short* __restrict__ ctx) {
  __shared__ __align__(16) unsigned char ldsK[2][64 * 64 * 2];
  __shared__ __align__(16) unsigned char ldsV[2][64 * 64 * 2];
  __shared__ __align__(16) unsigned char ldsP[4][16 * 64 * 2];

  const int tid = threadIdx.x, wid = tid >> 6, lane = tid & 63;
  const int g16 = lane >> 4, l16 = lane & 15;
  const int bh = blockIdx.y;
  const int q0 = blockIdx.x * 64;
  const int qr = q0 + wid * 16;  // wave's first q row

  // Q fragments (A-layout): row = qr + l16, d = ks*32 + g16*8 .. +7
  s16x8 qf[2];
#pragma unroll
  for (int ks = 0; ks < 2; ++ks) {
    qf[ks] = *(const s16x8*)(q + ((size_t)bh * SEQ + qr + l16) * 64 + ks * 32 + g16 * 8);
  }

  float mrow[4], lrow[4];
  f32x4 o[4];
#pragma unroll
  for (int i = 0; i < 4; ++i) {
    mrow[i] = -1e30f;
    lrow[i] = 0.f;
    o[i] = f32x4{0.f, 0.f, 0.f, 0.f};
  }

  const int nt = blockIdx.x + 1;  // causal: only tiles with kv0 <= q0

  auto stage = [&](int buf, int kt) {
    const int kv0 = kt * 64;
#pragma unroll
    for (int j = 0; j < 2; ++j) {
      const int cid = j * 256 + tid;  // 0..511, 16B chunks of 64x64 bf16 tile
      const int r = cid >> 3;
      const int c = (cid & 7) * 8;
      const int dst = (cid * 16) ^ ((r & 7) << 4);
      *(s16x8*)(ldsK[buf] + dst) =
          *(const s16x8*)(k + ((size_t)bh * SEQ + kv0 + r) * 64 + c);
      *(s16x8*)(ldsV[buf] + dst) =
          *(const s16x8*)(vT + ((size_t)bh * 64 + r) * SEQ + kv0 + c);
    }
  };

  stage(0, 0);
  __syncthreads();
  int buf = 0;
#pragma unroll 1
  for (int kt = 0; kt < nt; ++kt) {
    if (kt + 1 < nt) stage(buf ^ 1, kt + 1);
    const int kv0 = kt * 64;
    const bool active = kv0 <= qr + 15;  // wave-uniform
    if (active) {
      // --- QK^T: scores[16 q][64 kv] as 4 C-frags ---
      f32x4 sc[4];
#pragma unroll
      for (int jn = 0; jn < 4; ++jn) sc[jn] = f32x4{0.f, 0.f, 0.f, 0.f};
#pragma unroll
      for (int ks = 0; ks < 2; ++ks) {
        const int kb2 = (ks * 32 + g16 * 8) * 2;
#pragma unroll
        for (int jn = 0; jn < 4; ++jn) {
          const int row = jn * 16 + l16;
          s16x8 kf =
              *(const s16x8*)(ldsK[buf] + ((row * 128 + kb2) ^ ((row & 7) << 4)));
          sc[jn] = MFMA(qf[ks], kf, sc[jn]);
        }
      }
      // --- causal mask ---
      if (kv0 + 63 > qr) {
#pragma unroll
        for (int jn = 0; jn < 4; ++jn) {
          const int kvi = kv0 + jn * 16 + l16;
#pragma unroll
          for (int i = 0; i < 4; ++i) {
            if (kvi > qr + g16 * 4 + i) sc[jn][i] = -1e30f;
          }
        }
      }
      // --- online softmax ---
      float tmax[4];
#pragma unroll
      for (int i = 0; i < 4; ++i)
        tmax[i] = fmaxf(fmaxf(sc[0][i], sc[1][i]), fmaxf(sc[2][i], sc[3][i]));
#pragma unroll
      for (int off = 1; off < 16; off <<= 1)
#pragma unroll
        for (int i = 0; i < 4; ++i)
          tmax[i] = fmaxf(tmax[i], __shfl_xor(tmax[i], off, 64));
      float scale[4];
#pragma unroll
      for (int i = 0; i < 4; ++i) {
        const float mnew = fmaxf(mrow[i], tmax[i]);
        scale[i] = exp2f((mrow[i] - mnew) * LOG2E);
        mrow[i] = mnew;
      }
      float tsum[4] = {0.f, 0.f, 0.f, 0.f};
      unsigned char* pbase = &ldsP[wid][0];
#pragma unroll
      for (int jn = 0; jn < 4; ++jn) {
#pragma unroll
        for (int i = 0; i < 4; ++i) {
          const float p = exp2f((sc[jn][i] - mrow[i]) * LOG2E);
          tsum[i] += p;
          const int qrow = g16 * 4 + i;
          *(unsigned short*)(pbase +
                             (((qrow * 64 + jn * 16 + l16) * 2) ^ ((qrow & 7) << 4))) =
              f2bf(p);
        }
      }
#pragma unroll
      for (int off = 1; off < 16; off <<= 1)
#pragma unroll
        for (int i = 0; i < 4; ++i) tsum[i] += __shfl_xor(tsum[i], off, 64);
#pragma unroll
      for (int i = 0; i < 4; ++i) lrow[i] = lrow[i] * scale[i] + tsum[i];
#pragma unroll
      for (int jd = 0; jd < 4; ++jd)
#pragma unroll
        for (int i = 0; i < 4; ++i) o[jd][i] *= scale[i];
      // --- PV: o[16 q][64 d] += P[16][64] * V[64][64] ---
#pragma unroll
      for (int ks = 0; ks < 2; ++ks) {
        const int kb2 = (ks * 32 + g16 * 8) * 2;
        s16x8 pa = *(const s16x8*)(pbase + ((l16 * 128 + kb2) ^ ((l16 & 7) << 4)));
#pragma unroll
        for (int jd = 0; jd < 4; ++jd) {
          const int row = jd * 16 + l16;  // d index
          s16x8 vf =
              *(const s16x8*)(ldsV[buf] + ((row * 128 + kb2) ^ ((row & 7) << 4)));
          o[jd] = MFMA(pa, vf, o[jd]);
        }
      }
    }
    __syncthreads();
    buf ^= 1;
  }
  // --- epilogue: ctx[b*S + q][h*64 + d] ---
  const int b = bh >> 4, h = bh & 15;
#pragma unroll
  for (int jd = 0; jd < 4; ++jd) {
#pragma unroll
    for (int i = 0; i < 4; ++i) {
      const int qi = qr + g16 * 4 + i;
      const float v = o[jd][i] / lrow[i];
      ctx[((size_t)(b * SEQ + qi)) * D_MODEL + h * 64 + jd * 16 + l16] = f2bf(v);
    }
  }
}

extern "C" void kernel_launch(void* const* d_in, const int* in_sizes, int n_in,
                              void* d_out, int out_size, void* d_ws, size_t ws_size,
                              hipStream_t stream) {
  const float* Q = (const float*)d_in[0];
  const float* Kin = (const float*)d_in[1];
  const float* V = (const float*)d_in[2];
  // d_in[3] = mask: causal tril, implemented directly
  const float* Wq = (const float*)d_in[4];
  const float* bq = (const float*)d_in[5];
  const float* Wk = (const float*)d_in[6];
  const float* bk = (const float*)d_in[7];
  const float* Wv = (const float*)d_in[8];
  const float* bv = (const float*)d_in[9];
  const float* Wo = (const float*)d_in[10];
  const float* bo = (const float*)d_in[11];
  float* out = (float*)d_out;

  const size_t HSEQD = (size_t)NB * NH * SEQ * 64;  // 8.39M elements
  unsigned short* qb = (unsigned short*)d_ws;
  unsigned short* kb = qb + HSEQD;
  unsigned short* vTb = kb + HSEQD;
  unsigned short* ctx = vTb + HSEQD;

  dim3 blk(256);
  dim3 grid(D_MODEL / 128, NB * SEQ / 128);  // (8, 64)
  gemm_bt<0, 0><<<grid, blk, 0, stream>>>(Q, Wq, bq, qb);
  gemm_bt<0, 1><<<grid, blk, 0, stream>>>(Kin, Wk, bk, kb);
  gemm_bt<0, 2><<<grid, blk, 0, stream>>>(V, Wv, bv, vTb);
  attn_kernel<<<dim3(SEQ / 64, NB * NH), blk, 0, stream>>>(qb, kb, vTb, ctx);
  gemm_bt<1, 3><<<grid, blk, 0, stream>>>(ctx, Wo, bo, out);
}

// Round 3
// 407.846 us; speedup vs baseline: 1.4075x; 1.4075x over previous
//
#include <hip/hip_runtime.h>

#define DEV __device__ __forceinline__

typedef __attribute__((ext_vector_type(4))) float f32x4;
typedef __attribute__((ext_vector_type(4))) int i32x4;
typedef __attribute__((ext_vector_type(8))) short s16x8;
typedef __attribute__((ext_vector_type(8))) __bf16 bf16x8;

static constexpr int D_MODEL = 1024;
static constexpr int SEQ = 2048;
static constexpr int NB = 4;
static constexpr int NH = 16;

DEV unsigned short f2bf(float f) {
  unsigned int u = __builtin_bit_cast(unsigned int, f);
  u += 0x7fffu + ((u >> 16) & 1u);
  return (unsigned short)(u >> 16);
}

DEV s16x8 pack8(f32x4 a, f32x4 b) {
  s16x8 r;
  r[0] = (short)f2bf(a[0]); r[1] = (short)f2bf(a[1]);
  r[2] = (short)f2bf(a[2]); r[3] = (short)f2bf(a[3]);
  r[4] = (short)f2bf(b[0]); r[5] = (short)f2bf(b[1]);
  r[6] = (short)f2bf(b[2]); r[7] = (short)f2bf(b[3]);
  return r;
}

DEV f32x4 MFMA(s16x8 a, s16x8 b, f32x4 c) {
  return __builtin_amdgcn_mfma_f32_16x16x32_bf16(
      __builtin_bit_cast(bf16x8, a), __builtin_bit_cast(bf16x8, b), c, 0, 0, 0);
}

typedef const __attribute__((address_space(1))) void gas_t;
typedef __attribute__((address_space(3))) void las_t;
DEV void gload16(const void* g, void* l) {
  __builtin_amdgcn_global_load_lds((gas_t*)(unsigned long long)g,
                                   (las_t*)(unsigned int)(unsigned long long)l,
                                   16, 0, 0);
}

// ---------------- convert fp32 -> bf16 (7 tensors) ----------------
__global__ __launch_bounds__(256) void convert_all(
    const float* __restrict__ Q, const float* __restrict__ K,
    const float* __restrict__ V, const float* __restrict__ Wq,
    const float* __restrict__ Wk, const float* __restrict__ Wv,
    const float* __restrict__ Wo, unsigned short* __restrict__ ws) {
  constexpr int BIG = NB * SEQ * D_MODEL;  // 8388608
  constexpr int WN = D_MODEL * D_MODEL;    // 1048576
  constexpr int BIGB = BIG / 8 / 256;      // 4096 blocks
  constexpr int WB = WN / 8 / 256;         // 512 blocks
  const int blk = blockIdx.x;
  const float* src;
  unsigned short* dst;
  int boff;
  if (blk < 3 * BIGB) {
    const int r = blk / BIGB;
    boff = blk - r * BIGB;
    src = (r == 0) ? Q : ((r == 1) ? K : V);
    dst = ws + (size_t)r * BIG;
  } else {
    const int r = (blk - 3 * BIGB) / WB;
    boff = (blk - 3 * BIGB) - r * WB;
    src = (r == 0) ? Wq : ((r == 1) ? Wk : ((r == 2) ? Wv : Wo));
    dst = ws + (size_t)3 * BIG + (size_t)r * WN;
  }
  const size_t idx = ((size_t)boff * 256 + threadIdx.x) * 8;
  f32x4 a = *(const f32x4*)(src + idx);
  f32x4 b = *(const f32x4*)(src + idx + 4);
  *(s16x8*)(dst + idx) = pack8(a, b);
}

// ---------------- GEMM: C[m,n] = sum_k A[m,k]*W[n,k] + bias[n] ----------------
// A,W bf16. OUT_MODE 0: q bf16 [BH][S][64] *0.125*log2(e); 1: k bf16 [BH][S][64];
// 2: vT bf16 [BH][64][S]; 3: fp32 [M][1024]
template <int OUT_MODE>
__global__ __launch_bounds__(256) void gemm_bt(const unsigned short* __restrict__ Ap,
                                               const unsigned short* __restrict__ Wp,
                                               const float* __restrict__ bias,
                                               void* __restrict__ outp) {
  constexpr int K = 1024, BK = 64;
  __shared__ __align__(16) unsigned char ldsA[2][128 * BK * 2];
  __shared__ __align__(16) unsigned char ldsB[2][128 * BK * 2];

  const int tid = threadIdx.x;
  const int wid = tid >> 6, lane = tid & 63;
  const int g16 = lane >> 4, l16 = lane & 15;
  const int m0 = blockIdx.y * 128;
  const int n0 = blockIdx.x * 128;
  const int wm = (wid >> 1) * 64, wn = (wid & 1) * 64;

  f32x4 acc[4][4];
#pragma unroll
  for (int a = 0; a < 4; ++a)
#pragma unroll
    for (int b = 0; b < 4; ++b) acc[a][b] = f32x4{0.f, 0.f, 0.f, 0.f};

  // pre-swizzled-source staging via global_load_lds (LDS layout identical to
  // writing chunk (r,c) at byte (r*128 + c*16) ^ ((r&7)<<4))
  auto stage = [&](int buf, int kt) {
    const int k0 = kt * BK;
#pragma unroll
    for (int t = 0; t < 4; ++t) {
      const int seg = wid * 4 + t;
      const int cid = seg * 64 + lane;
      const int r = cid >> 3;
      const int c = ((cid & 7) ^ (r & 7)) * 8;
      gload16(Ap + (size_t)(m0 + r) * K + k0 + c, ldsA[buf] + seg * 1024);
      gload16(Wp + (size_t)(n0 + r) * K + k0 + c, ldsB[buf] + seg * 1024);
    }
  };

  auto compute = [&](int buf) {
#pragma unroll
    for (int ks = 0; ks < 2; ++ks) {
      const int kb2 = (ks * 32 + g16 * 8) * 2;
      s16x8 af[4], bfr[4];
#pragma unroll
      for (int mf = 0; mf < 4; ++mf) {
        const int row = wm + mf * 16 + l16;
        af[mf] = *(const s16x8*)(ldsA[buf] + ((row * 128 + kb2) ^ ((row & 7) << 4)));
      }
#pragma unroll
      for (int nf = 0; nf < 4; ++nf) {
        const int row = wn + nf * 16 + l16;
        bfr[nf] = *(const s16x8*)(ldsB[buf] + ((row * 128 + kb2) ^ ((row & 7) << 4)));
      }
#pragma unroll
      for (int mf = 0; mf < 4; ++mf)
#pragma unroll
        for (int nf = 0; nf < 4; ++nf)
          acc[mf][nf] = MFMA(af[mf], bfr[nf], acc[mf][nf]);
    }
  };

  stage(0, 0);
  __syncthreads();
  int buf = 0;
#pragma unroll 1
  for (int kt = 0; kt < K / BK; ++kt) {
    if (kt + 1 < K / BK) stage(buf ^ 1, kt + 1);
    compute(buf);
    __syncthreads();
    buf ^= 1;
  }

#pragma unroll
  for (int nf = 0; nf < 4; ++nf) {
    const int n = n0 + wn + nf * 16 + l16;
    const float bv = bias[n];
#pragma unroll
    for (int mf = 0; mf < 4; ++mf) {
#pragma unroll
      for (int i = 0; i < 4; ++i) {
        const int m = m0 + wm + mf * 16 + g16 * 4 + i;
        float v = acc[mf][nf][i] + bv;
        if constexpr (OUT_MODE == 0 || OUT_MODE == 1) {
          if constexpr (OUT_MODE == 0) v *= 0.18033688011112042f;  // 0.125*log2(e)
          const int bh = (m >> 11) * NH + (n >> 6);
          ((unsigned short*)outp)[((size_t)bh * SEQ + (m & 2047)) * 64 + (n & 63)] =
              f2bf(v);
        } else if constexpr (OUT_MODE == 2) {
          const int bh = (m >> 11) * NH + (n >> 6);
          ((unsigned short*)outp)[((size_t)bh * 64 + (n & 63)) * SEQ + (m & 2047)] =
              f2bf(v);
        } else {
          ((float*)outp)[(size_t)m * D_MODEL + n] = v;
        }
      }
    }
  }
}

// ---------------- causal flash attention, dual q-tile, swapped QK^T ----------------
// grid (16, B*H). Block jj handles q-tiles tA=31-jj and tB=jj (uniform 33 units).
// q,k: [BH][S][64] bf16 (q pre-scaled by 0.125*log2e). vT: [BH][64][S] bf16.
// Scores computed as mfma(K,Q): sc[jn][i] = S[kv=jn*16+g16*4+i][q=l16].
__global__ __launch_bounds__(256) void attn_kernel(
    const unsigned short* __restrict__ q, const unsigned short* __restrict__ k,
    const unsigned short* __restrict__ vT, unsigned short* __restrict__ ctx) {
  __shared__ __align__(16) unsigned char ldsK[2][64 * 64 * 2];
  __shared__ __align__(16) unsigned char ldsV[2][64 * 64 * 2];

  const int tid = threadIdx.x, wid = tid >> 6, lane = tid & 63;
  const int g16 = lane >> 4, l16 = lane & 15;
  const int bh = blockIdx.y;
  const int jj = blockIdx.x;
  const int tA = 31 - jj, tB = jj;
  const int qrA = tA * 64 + wid * 16, qrB = tB * 64 + wid * 16;
  const size_t qbase = (size_t)bh * SEQ;

  s16x8 qfA[2], qfB[2];
#pragma unroll
  for (int ks = 0; ks < 2; ++ks) {
    qfA[ks] = *(const s16x8*)(q + (qbase + qrA + l16) * 64 + ks * 32 + g16 * 8);
    qfB[ks] = *(const s16x8*)(q + (qbase + qrB + l16) * 64 + ks * 32 + g16 * 8);
  }

  float mA = -3.0e38f, lA = 0.f, mB = -3.0e38f, lB = 0.f;
  f32x4 oA[4], oB[4];
#pragma unroll
  for (int i = 0; i < 4; ++i) {
    oA[i] = f32x4{0.f, 0.f, 0.f, 0.f};
    oB[i] = f32x4{0.f, 0.f, 0.f, 0.f};
  }

  // shuffle constants
  const int srcb = (lane & 48) + ((lane & 48) >> 2);        // lane (g, g*4) in own group
  const int srcA_lane = ((2 * g16) & 3) * 16 + l16;         // e0..3 source
  const int srcB_lane = ((2 * g16 + 1) & 3) * 16 + l16;     // e4..7 source
  const bool jsel = (g16 >> 1) != 0;                        // jn = 2ks + (g16>>1)

  auto stage = [&](int buf, int kt) {
    const int kv0 = kt * 64;
#pragma unroll
    for (int t = 0; t < 2; ++t) {
      const int seg = wid * 2 + t;
      const int cid = seg * 64 + lane;
      const int r = cid >> 3;
      const int c = ((cid & 7) ^ (r & 7)) * 8;
      gload16(k + (qbase + kv0 + r) * 64 + c, ldsK[buf] + seg * 1024);
      gload16(vT + ((size_t)bh * 64 + r) * SEQ + kv0 + c, ldsV[buf] + seg * 1024);
    }
  };

  // mask(optional) + online softmax + rescale o + build PV A-frags in-register
  auto softmax = [&](f32x4* sc, float& mrun, float& lrun, f32x4* o, bool diag,
                     s16x8* pa) {
    if (diag) {
#pragma unroll
      for (int jn = 0; jn < 4; ++jn)
#pragma unroll
        for (int i = 0; i < 4; ++i)
          if (jn * 16 + g16 * 4 + i > wid * 16 + l16) sc[jn][i] = -3.0e38f;
    }
    float tm = sc[0][0];
#pragma unroll
    for (int jn = 0; jn < 4; ++jn)
#pragma unroll
      for (int i = 0; i < 4; ++i) tm = fmaxf(tm, sc[jn][i]);
    tm = fmaxf(tm, __shfl_xor(tm, 16, 64));
    tm = fmaxf(tm, __shfl_xor(tm, 32, 64));
    const float mnew = fmaxf(mrun, tm);
    const float sca = exp2f(mrun - mnew);
    mrun = mnew;
    float tsum = 0.f;
    unsigned int pk[4][2];
#pragma unroll
    for (int jn = 0; jn < 4; ++jn) {
      const float p0 = exp2f(sc[jn][0] - mnew);
      const float p1 = exp2f(sc[jn][1] - mnew);
      const float p2 = exp2f(sc[jn][2] - mnew);
      const float p3 = exp2f(sc[jn][3] - mnew);
      tsum += (p0 + p1) + (p2 + p3);
      pk[jn][0] = (unsigned int)f2bf(p0) | ((unsigned int)f2bf(p1) << 16);
      pk[jn][1] = (unsigned int)f2bf(p2) | ((unsigned int)f2bf(p3) << 16);
    }
    tsum += __shfl_xor(tsum, 16, 64);
    tsum += __shfl_xor(tsum, 32, 64);
    lrun = lrun * sca + tsum;
#pragma unroll
    for (int i = 0; i < 4; ++i) {
      const float si = __shfl(sca, srcb + i, 64);
#pragma unroll
      for (int jd = 0; jd < 4; ++jd) o[jd][i] *= si;
    }
    // pa[ks] element e = P[kv = ks*32 + g16*8 + e][q = l16]
#pragma unroll
    for (int ks = 0; ks < 2; ++ks) {
      i32x4 w;
      int a0 = __shfl((int)pk[2 * ks][0], srcA_lane, 64);
      int a1 = __shfl((int)pk[2 * ks + 1][0], srcA_lane, 64);
      w[0] = jsel ? a1 : a0;
      int b0 = __shfl((int)pk[2 * ks][1], srcA_lane, 64);
      int b1 = __shfl((int)pk[2 * ks + 1][1], srcA_lane, 64);
      w[1] = jsel ? b1 : b0;
      int c0 = __shfl((int)pk[2 * ks][0], srcB_lane, 64);
      int c1 = __shfl((int)pk[2 * ks + 1][0], srcB_lane, 64);
      w[2] = jsel ? c1 : c0;
      int d0 = __shfl((int)pk[2 * ks][1], srcB_lane, 64);
      int d1 = __shfl((int)pk[2 * ks + 1][1], srcB_lane, 64);
      w[3] = jsel ? d1 : d0;
      pa[ks] = __builtin_bit_cast(s16x8, w);
    }
  };

  stage(0, 0);
  __syncthreads();
  int buf = 0;
#pragma unroll 1
  for (int kt = 0; kt <= tA; ++kt) {
    if (kt < tA) stage(buf ^ 1, kt + 1);
    const bool doB = (kt <= tB);
    f32x4 scA[4], scB[4];
#pragma unroll
    for (int jn = 0; jn < 4; ++jn) {
      scA[jn] = f32x4{0.f, 0.f, 0.f, 0.f};
      scB[jn] = f32x4{0.f, 0.f, 0.f, 0.f};
    }
#pragma unroll
    for (int ks = 0; ks < 2; ++ks) {
      const int kb2 = (ks * 32 + g16 * 8) * 2;
#pragma unroll
      for (int jn = 0; jn < 4; ++jn) {
        const int row = jn * 16 + l16;
        s16x8 kf = *(const s16x8*)(ldsK[buf] + ((row * 128 + kb2) ^ ((row & 7) << 4)));
        scA[jn] = MFMA(kf, qfA[ks], scA[jn]);
        if (doB) scB[jn] = MFMA(kf, qfB[ks], scB[jn]);
      }
    }
    s16x8 paA[2], paB[2];
    softmax(scA, mA, lA, oA, kt == tA, paA);
    if (doB) softmax(scB, mB, lB, oB, kt == tB, paB);
#pragma unroll
    for (int ks = 0; ks < 2; ++ks) {
      const int kb2 = (ks * 32 + g16 * 8) * 2;
#pragma unroll
      for (int jd = 0; jd < 4; ++jd) {
        const int row = jd * 16 + l16;
        s16x8 vf = *(const s16x8*)(ldsV[buf] + ((row * 128 + kb2) ^ ((row & 7) << 4)));
        oA[jd] = MFMA(paA[ks], vf, oA[jd]);
        if (doB) oB[jd] = MFMA(paB[ks], vf, oB[jd]);
      }
    }
    __syncthreads();
    buf ^= 1;
  }

  const int b = bh >> 4, h = bh & 15;
  auto epi = [&](const f32x4* o, float lrun, int qr) {
#pragma unroll
    for (int i = 0; i < 4; ++i) {
      const float li = 1.f / __shfl(lrun, srcb + i, 64);
      const int qi = qr + g16 * 4 + i;
      unsigned short* dst = ctx + ((size_t)(b * SEQ + qi)) * D_MODEL + h * 64;
#pragma unroll
      for (int jd = 0; jd < 4; ++jd) dst[jd * 16 + l16] = f2bf(o[jd][i] * li);
    }
  };
  epi(oA, lA, qrA);
  epi(oB, lB, qrB);
}

extern "C" void kernel_launch(void* const* d_in, const int* in_sizes, int n_in,
                              void* d_out, int out_size, void* d_ws, size_t ws_size,
                              hipStream_t stream) {
  const float* Q = (const float*)d_in[0];
  const float* Kin = (const float*)d_in[1];
  const float* V = (const float*)d_in[2];
  // d_in[3] = mask: causal tril, implemented analytically
  const float* Wq = (const float*)d_in[4];
  const float* bq = (const float*)d_in[5];
  const float* Wk = (const float*)d_in[6];
  const float* bk = (const float*)d_in[7];
  const float* Wv = (const float*)d_in[8];
  const float* bv = (const float*)d_in[9];
  const float* Wo = (const float*)d_in[10];
  const float* bo = (const float*)d_in[11];
  float* out = (float*)d_out;

  constexpr size_t BIG = (size_t)NB * SEQ * D_MODEL;  // 8388608
  constexpr size_t WN = (size_t)D_MODEL * D_MODEL;    // 1048576
  unsigned short* ws = (unsigned short*)d_ws;
  unsigned short* Qb = ws;
  unsigned short* Kb = ws + BIG;
  unsigned short* Vb = ws + 2 * BIG;
  unsigned short* Wqb = ws + 3 * BIG;
  unsigned short* Wkb = Wqb + WN;
  unsigned short* Wvb = Wkb + WN;
  unsigned short* Wob = Wvb + WN;
  unsigned short* qb = Wob + WN;
  unsigned short* kb = qb + BIG;
  unsigned short* vTb = kb + BIG;
  unsigned short* ctx = Qb;  // Qb dead after the q-projection GEMM

  dim3 blk(256);
  convert_all<<<dim3(3 * 4096 + 4 * 512), blk, 0, stream>>>(Q, Kin, V, Wq, Wk, Wv,
                                                            Wo, ws);
  dim3 grid(D_MODEL / 128, NB * SEQ / 128);  // (8, 64)
  gemm_bt<0><<<grid, blk, 0, stream>>>(Qb, Wqb, bq, qb);
  gemm_bt<1><<<grid, blk, 0, stream>>>(Kb, Wkb, bk, kb);
  gemm_bt<2><<<grid, blk, 0, stream>>>(Vb, Wvb, bv, vTb);
  attn_kernel<<<dim3(16, NB * NH), blk, 0, stream>>>(qb, kb, vTb, ctx);
  gemm_bt<3><<<grid, blk, 0, stream>>>(ctx, Wob, bo, out);
}

// Round 4
// 391.896 us; speedup vs baseline: 1.4648x; 1.0407x over previous
//
#include <hip/hip_runtime.h>

#define DEV __device__ __forceinline__

typedef __attribute__((ext_vector_type(4))) float f32x4;
typedef __attribute__((ext_vector_type(8))) short s16x8;
typedef __attribute__((ext_vector_type(8))) __bf16 bf16x8;

static constexpr int D_MODEL = 1024;
static constexpr int SEQ = 2048;
static constexpr int NB = 4;
static constexpr int NH = 16;

DEV unsigned short f2bf(float f) {
  __bf16 h = (__bf16)f;  // RNE; compiler packs pairs into v_cvt_pk_bf16_f32
  return __builtin_bit_cast(unsigned short, h);
}

DEV s16x8 pack8(f32x4 a, f32x4 b) {
  bf16x8 r;
  r[0] = (__bf16)a[0]; r[1] = (__bf16)a[1]; r[2] = (__bf16)a[2]; r[3] = (__bf16)a[3];
  r[4] = (__bf16)b[0]; r[5] = (__bf16)b[1]; r[6] = (__bf16)b[2]; r[7] = (__bf16)b[3];
  return __builtin_bit_cast(s16x8, r);
}

DEV f32x4 MFMA(s16x8 a, s16x8 b, f32x4 c) {
  return __builtin_amdgcn_mfma_f32_16x16x32_bf16(
      __builtin_bit_cast(bf16x8, a), __builtin_bit_cast(bf16x8, b), c, 0, 0, 0);
}

typedef const __attribute__((address_space(1))) void gas_t;
typedef __attribute__((address_space(3))) void las_t;
DEV void gload16(const void* g, void* l) {
  __builtin_amdgcn_global_load_lds((gas_t*)(unsigned long long)g,
                                   (las_t*)(unsigned int)(unsigned long long)l,
                                   16, 0, 0);
}

// ---------------- convert fp32 -> bf16 (7 tensors) ----------------
__global__ __launch_bounds__(256) void convert_all(
    const float* __restrict__ Q, const float* __restrict__ K,
    const float* __restrict__ V, const float* __restrict__ Wq,
    const float* __restrict__ Wk, const float* __restrict__ Wv,
    const float* __restrict__ Wo, unsigned short* __restrict__ ws) {
  constexpr int BIG = NB * SEQ * D_MODEL;  // 8388608
  constexpr int WN = D_MODEL * D_MODEL;    // 1048576
  constexpr int BIGB = BIG / 8 / 256;      // 4096 blocks
  constexpr int WB = WN / 8 / 256;         // 512 blocks
  const int blk = blockIdx.x;
  const float* src;
  unsigned short* dst;
  int boff;
  if (blk < 3 * BIGB) {
    const int r = blk / BIGB;
    boff = blk - r * BIGB;
    src = (r == 0) ? Q : ((r == 1) ? K : V);
    dst = ws + (size_t)r * BIG;
  } else {
    const int r = (blk - 3 * BIGB) / WB;
    boff = (blk - 3 * BIGB) - r * WB;
    src = (r == 0) ? Wq : ((r == 1) ? Wk : ((r == 2) ? Wv : Wo));
    dst = ws + (size_t)3 * BIG + (size_t)r * WN;
  }
  const size_t idx = ((size_t)boff * 256 + threadIdx.x) * 8;
  f32x4 a = *(const f32x4*)(src + idx);
  f32x4 b = *(const f32x4*)(src + idx + 4);
  *(s16x8*)(dst + idx) = pack8(a, b);
}

// ---------------- fused QKV GEMM (grid.z selects q/k/v) ----------------
// C[m,n] = sum_k A[m,k]*W[n,k] + bias[n]
// z=0: q bf16 [BH][S][64] * 0.125*log2(e); z=1: k bf16 [BH][S][64];
// z=2: vT bf16 [BH][64][S]
__global__ __launch_bounds__(256) void qkv_gemm(const unsigned short* __restrict__ ws,
                                                const float* __restrict__ bq,
                                                const float* __restrict__ bk,
                                                const float* __restrict__ bv,
                                                unsigned short* __restrict__ outb) {
  constexpr int K = 1024, BK = 64;
  constexpr size_t BIG = (size_t)NB * SEQ * D_MODEL;
  constexpr size_t WN = (size_t)D_MODEL * D_MODEL;
  __shared__ __align__(16) unsigned char ldsA[2][128 * BK * 2];
  __shared__ __align__(16) unsigned char ldsB[2][128 * BK * 2];

  const int z = blockIdx.z;
  const unsigned short* Ap = ws + (size_t)z * BIG;
  const unsigned short* Wp = ws + 3 * BIG + (size_t)z * WN;
  const float* bias = (z == 0) ? bq : ((z == 1) ? bk : bv);
  unsigned short* outp = outb + (size_t)z * BIG;

  const int tid = threadIdx.x;
  const int wid = tid >> 6, lane = tid & 63;
  const int g16 = lane >> 4, l16 = lane & 15;
  const int m0 = blockIdx.y * 128;
  const int n0 = blockIdx.x * 128;
  const int wm = (wid >> 1) * 64, wn = (wid & 1) * 64;

  f32x4 acc[4][4];
#pragma unroll
  for (int a = 0; a < 4; ++a)
#pragma unroll
    for (int b = 0; b < 4; ++b) acc[a][b] = f32x4{0.f, 0.f, 0.f, 0.f};

  auto stage = [&](int buf, int kt) {
    const int k0 = kt * BK;
#pragma unroll
    for (int t = 0; t < 4; ++t) {
      const int seg = wid * 4 + t;
      const int cid = seg * 64 + lane;
      const int r = cid >> 3;
      const int c = ((cid & 7) ^ (r & 7)) * 8;
      gload16(Ap + (size_t)(m0 + r) * K + k0 + c, ldsA[buf] + seg * 1024);
      gload16(Wp + (size_t)(n0 + r) * K + k0 + c, ldsB[buf] + seg * 1024);
    }
  };

  auto compute = [&](int buf) {
#pragma unroll
    for (int ks = 0; ks < 2; ++ks) {
      const int kb2 = (ks * 32 + g16 * 8) * 2;
      s16x8 af[4], bfr[4];
#pragma unroll
      for (int mf = 0; mf < 4; ++mf) {
        const int row = wm + mf * 16 + l16;
        af[mf] = *(const s16x8*)(ldsA[buf] + ((row * 128 + kb2) ^ ((row & 7) << 4)));
      }
#pragma unroll
      for (int nf = 0; nf < 4; ++nf) {
        const int row = wn + nf * 16 + l16;
        bfr[nf] = *(const s16x8*)(ldsB[buf] + ((row * 128 + kb2) ^ ((row & 7) << 4)));
      }
#pragma unroll
      for (int mf = 0; mf < 4; ++mf)
#pragma unroll
        for (int nf = 0; nf < 4; ++nf)
          acc[mf][nf] = MFMA(af[mf], bfr[nf], acc[mf][nf]);
    }
  };

  stage(0, 0);
  __syncthreads();
  int buf = 0;
#pragma unroll 1
  for (int kt = 0; kt < K / BK; ++kt) {
    if (kt + 1 < K / BK) stage(buf ^ 1, kt + 1);
    compute(buf);
    __syncthreads();
    buf ^= 1;
  }

#pragma unroll
  for (int nf = 0; nf < 4; ++nf) {
    const int n = n0 + wn + nf * 16 + l16;
    const float bv_ = bias[n];
#pragma unroll
    for (int mf = 0; mf < 4; ++mf) {
#pragma unroll
      for (int i = 0; i < 4; ++i) {
        const int m = m0 + wm + mf * 16 + g16 * 4 + i;
        float v = acc[mf][nf][i] + bv_;
        if (z == 0) v *= 0.18033688011112042f;  // 0.125*log2(e)
        const int bh = (m >> 11) * NH + (n >> 6);
        if (z < 2) {
          outp[((size_t)bh * SEQ + (m & 2047)) * 64 + (n & 63)] = f2bf(v);
        } else {
          outp[((size_t)bh * 64 + (n & 63)) * SEQ + (m & 2047)] = f2bf(v);
        }
      }
    }
  }
}

// ---------------- output GEMM: fp32 out ----------------
__global__ __launch_bounds__(256) void gemm_out(const unsigned short* __restrict__ Ap,
                                                const unsigned short* __restrict__ Wp,
                                                const float* __restrict__ bias,
                                                float* __restrict__ outp) {
  constexpr int K = 1024, BK = 64;
  __shared__ __align__(16) unsigned char ldsA[2][128 * BK * 2];
  __shared__ __align__(16) unsigned char ldsB[2][128 * BK * 2];

  const int tid = threadIdx.x;
  const int wid = tid >> 6, lane = tid & 63;
  const int g16 = lane >> 4, l16 = lane & 15;
  const int m0 = blockIdx.y * 128;
  const int n0 = blockIdx.x * 128;
  const int wm = (wid >> 1) * 64, wn = (wid & 1) * 64;

  f32x4 acc[4][4];
#pragma unroll
  for (int a = 0; a < 4; ++a)
#pragma unroll
    for (int b = 0; b < 4; ++b) acc[a][b] = f32x4{0.f, 0.f, 0.f, 0.f};

  auto stage = [&](int buf, int kt) {
    const int k0 = kt * BK;
#pragma unroll
    for (int t = 0; t < 4; ++t) {
      const int seg = wid * 4 + t;
      const int cid = seg * 64 + lane;
      const int r = cid >> 3;
      const int c = ((cid & 7) ^ (r & 7)) * 8;
      gload16(Ap + (size_t)(m0 + r) * K + k0 + c, ldsA[buf] + seg * 1024);
      gload16(Wp + (size_t)(n0 + r) * K + k0 + c, ldsB[buf] + seg * 1024);
    }
  };

  auto compute = [&](int buf) {
#pragma unroll
    for (int ks = 0; ks < 2; ++ks) {
      const int kb2 = (ks * 32 + g16 * 8) * 2;
      s16x8 af[4], bfr[4];
#pragma unroll
      for (int mf = 0; mf < 4; ++mf) {
        const int row = wm + mf * 16 + l16;
        af[mf] = *(const s16x8*)(ldsA[buf] + ((row * 128 + kb2) ^ ((row & 7) << 4)));
      }
#pragma unroll
      for (int nf = 0; nf < 4; ++nf) {
        const int row = wn + nf * 16 + l16;
        bfr[nf] = *(const s16x8*)(ldsB[buf] + ((row * 128 + kb2) ^ ((row & 7) << 4)));
      }
#pragma unroll
      for (int mf = 0; mf < 4; ++mf)
#pragma unroll
        for (int nf = 0; nf < 4; ++nf)
          acc[mf][nf] = MFMA(af[mf], bfr[nf], acc[mf][nf]);
    }
  };

  stage(0, 0);
  __syncthreads();
  int buf = 0;
#pragma unroll 1
  for (int kt = 0; kt < K / BK; ++kt) {
    if (kt + 1 < K / BK) stage(buf ^ 1, kt + 1);
    compute(buf);
    __syncthreads();
    buf ^= 1;
  }

#pragma unroll
  for (int nf = 0; nf < 4; ++nf) {
    const int n = n0 + wn + nf * 16 + l16;
    const float bv_ = bias[n];
#pragma unroll
    for (int mf = 0; mf < 4; ++mf) {
#pragma unroll
      for (int i = 0; i < 4; ++i) {
        const int m = m0 + wm + mf * 16 + g16 * 4 + i;
        outp[(size_t)m * D_MODEL + n] = acc[mf][nf][i] + bv_;
      }
    }
  }
}

// ---------------- causal flash attention ----------------
// grid (16, B*H). Block jj handles q-tiles tA=31-jj and tB=jj (uniform 33 units).
// K MFMA rows permuted by F(jn,r)=32(jn&1)+8(r>>2)+4(jn>>1)+(r&3) so that the
// P matrix lands lane-local in the PV A-fragment layout (zero shuffles).
// LDS swizzle xi(r) = (r&3)|(((r>>3)&1)<<2) on both stage-source and read.
__global__ __launch_bounds__(256) void attn_kernel(
    const unsigned short* __restrict__ q, const unsigned short* __restrict__ k,
    const unsigned short* __restrict__ vT, unsigned short* __restrict__ ctx) {
  __shared__ __align__(16) unsigned char ldsK[2][64 * 64 * 2];
  __shared__ __align__(16) unsigned char ldsV[2][64 * 64 * 2];

  const int tid = threadIdx.x, wid = tid >> 6, lane = tid & 63;
  const int g16 = lane >> 4, l16 = lane & 15;
  const int bh = blockIdx.y;
  const int jj = blockIdx.x;
  const int tA = 31 - jj, tB = jj;
  const int qrA = tA * 64 + wid * 16, qrB = tB * 64 + wid * 16;
  const size_t qbase = (size_t)bh * SEQ;

  s16x8 qfA[2], qfB[2];
#pragma unroll
  for (int ks = 0; ks < 2; ++ks) {
    qfA[ks] = *(const s16x8*)(q + (qbase + qrA + l16) * 64 + ks * 32 + g16 * 8);
    qfB[ks] = *(const s16x8*)(q + (qbase + qrB + l16) * 64 + ks * 32 + g16 * 8);
  }

  float mA = -3.0e38f, lA = 0.f, mB = -3.0e38f, lB = 0.f;
  f32x4 oA[4], oB[4];
#pragma unroll
  for (int i = 0; i < 4; ++i) {
    oA[i] = f32x4{0.f, 0.f, 0.f, 0.f};
    oB[i] = f32x4{0.f, 0.f, 0.f, 0.f};
  }

  const int srcb = (lane & 48) + ((lane & 48) >> 2);  // lane (g, 4g) of own group

  // K-read lane base: row part 8*(l16>>2)+(l16&3); xi(F(jn,l16)) == l16&7
  const int kRowB = (8 * (l16 >> 2) + (l16 & 3)) * 128;
  // V-read: row = 16*jd + l16; xi = (l16&3)|((l16>>3)<<2)
  const int vRowB = l16 * 128;
  const int xiV = ((l16 & 3) | ((l16 >> 3) << 2)) << 4;
  const int xiK = (l16 & 7) << 4;

  auto stage = [&](int buf, int kt) {
    const int kv0 = kt * 64;
#pragma unroll
    for (int t = 0; t < 2; ++t) {
      const int seg = wid * 2 + t;
      const int cid = seg * 64 + lane;
      const int r = cid >> 3;
      const int xi = (r & 3) | (((r >> 3) & 1) << 2);
      const int c = ((cid & 7) ^ xi) * 8;
      gload16(k + (qbase + kv0 + r) * 64 + c, ldsK[buf] + seg * 1024);
      gload16(vT + ((size_t)bh * 64 + r) * SEQ + kv0 + c, ldsV[buf] + seg * 1024);
    }
  };

  // online softmax with defer-max; P lands lane-local for PV
  auto softmax = [&](f32x4* sc, float& mrun, float& lrun, f32x4* o, bool diag,
                     s16x8* pa) {
    if (diag) {
#pragma unroll
      for (int jn = 0; jn < 4; ++jn)
#pragma unroll
        for (int i = 0; i < 4; ++i) {
          const int kvp = 32 * (jn & 1) + 8 * g16 + 4 * (jn >> 1) + i;
          if (kvp > wid * 16 + l16) sc[jn][i] = -3.0e38f;
        }
    }
    float pm = fmaxf(fmaxf(fmaxf(sc[0][0], sc[0][1]), fmaxf(sc[0][2], sc[0][3])),
                     fmaxf(fmaxf(sc[1][0], sc[1][1]), fmaxf(sc[1][2], sc[1][3])));
    pm = fmaxf(pm,
               fmaxf(fmaxf(fmaxf(sc[2][0], sc[2][1]), fmaxf(sc[2][2], sc[2][3])),
                     fmaxf(fmaxf(sc[3][0], sc[3][1]), fmaxf(sc[3][2], sc[3][3]))));
    pm = fmaxf(pm, __shfl_xor(pm, 16, 64));
    pm = fmaxf(pm, __shfl_xor(pm, 32, 64));
    if (__any(pm > mrun + 8.0f)) {  // defer-max: rescale only on large growth
      const float mnew = fmaxf(mrun, pm);
      const float sca = exp2f(mrun - mnew);
      lrun *= sca;
#pragma unroll
      for (int i = 0; i < 4; ++i) {
        const float si = __shfl(sca, srcb + i, 64);
#pragma unroll
        for (int jd = 0; jd < 4; ++jd) o[jd][i] *= si;
      }
      mrun = mnew;
    }
    float tsum = 0.f;
#pragma unroll
    for (int jn = 0; jn < 4; ++jn) {
#pragma unroll
      for (int i = 0; i < 4; ++i) sc[jn][i] = exp2f(sc[jn][i] - mrun);
      tsum += (sc[jn][0] + sc[jn][1]) + (sc[jn][2] + sc[jn][3]);
    }
    tsum += __shfl_xor(tsum, 16, 64);
    tsum += __shfl_xor(tsum, 32, 64);
    lrun += tsum;
    // pa[ks] element e = P[q=l16][kv=32ks+8g16+e] = sc[2*(e>>2)+ks][e&3]
#pragma unroll
    for (int ks = 0; ks < 2; ++ks) {
      bf16x8 t;
      t[0] = (__bf16)sc[ks][0]; t[1] = (__bf16)sc[ks][1];
      t[2] = (__bf16)sc[ks][2]; t[3] = (__bf16)sc[ks][3];
      t[4] = (__bf16)sc[ks + 2][0]; t[5] = (__bf16)sc[ks + 2][1];
      t[6] = (__bf16)sc[ks + 2][2]; t[7] = (__bf16)sc[ks + 2][3];
      pa[ks] = __builtin_bit_cast(s16x8, t);
    }
  };

  stage(0, 0);
  __syncthreads();
  int buf = 0;
#pragma unroll 1
  for (int kt = 0; kt <= tA; ++kt) {
    if (kt < tA) stage(buf ^ 1, kt + 1);
    const bool doB = (kt <= tB);
    f32x4 scA[4], scB[4];
#pragma unroll
    for (int jn = 0; jn < 4; ++jn) {
      scA[jn] = f32x4{0.f, 0.f, 0.f, 0.f};
      scB[jn] = f32x4{0.f, 0.f, 0.f, 0.f};
    }
    __builtin_amdgcn_s_setprio(1);
#pragma unroll
    for (int ks = 0; ks < 2; ++ks) {
      const int klane = (ldsK[buf] - ldsK[0]) ? 0 : 0;  // (no-op; keep structure)
      const int kb = ((64 * ks + 16 * g16) ^ xiK) + kRowB;
#pragma unroll
      for (int jn = 0; jn < 4; ++jn) {
        // row F(jn,l16): imm offset 4096*(jn&1) + 512*(jn>>1)
        const int off = kb + 4096 * (jn & 1) + 512 * (jn >> 1);
        s16x8 kf = *(const s16x8*)(ldsK[buf] + off);
        scA[jn] = MFMA(kf, qfA[ks], scA[jn]);
        if (doB) scB[jn] = MFMA(kf, qfB[ks], scB[jn]);
      }
    }
    __builtin_amdgcn_s_setprio(0);
    s16x8 paA[2], paB[2];
    softmax(scA, mA, lA, oA, kt == tA, paA);
    if (doB) softmax(scB, mB, lB, oB, kt == tB, paB);
    __builtin_amdgcn_s_setprio(1);
#pragma unroll
    for (int ks = 0; ks < 2; ++ks) {
      const int vb = ((64 * ks + 16 * g16) ^ xiV) + vRowB;
#pragma unroll
      for (int jd = 0; jd < 4; ++jd) {
        s16x8 vf = *(const s16x8*)(ldsV[buf] + vb + 2048 * jd);
        oA[jd] = MFMA(paA[ks], vf, oA[jd]);
        if (doB) oB[jd] = MFMA(paB[ks], vf, oB[jd]);
      }
    }
    __builtin_amdgcn_s_setprio(0);
    __syncthreads();
    buf ^= 1;
  }

  const int b = bh >> 4, h = bh & 15;
  auto epi = [&](const f32x4* o, float lrun, int qr) {
#pragma unroll
    for (int i = 0; i < 4; ++i) {
      const float li = 1.f / __shfl(lrun, srcb + i, 64);
      const int qi = qr + g16 * 4 + i;
      unsigned short* dst = ctx + ((size_t)(b * SEQ + qi)) * D_MODEL + h * 64;
#pragma unroll
      for (int jd = 0; jd < 4; ++jd) dst[jd * 16 + l16] = f2bf(o[jd][i] * li);
    }
  };
  epi(oA, lA, qrA);
  epi(oB, lB, qrB);
}

extern "C" void kernel_launch(void* const* d_in, const int* in_sizes, int n_in,
                              void* d_out, int out_size, void* d_ws, size_t ws_size,
                              hipStream_t stream) {
  const float* Q = (const float*)d_in[0];
  const float* Kin = (const float*)d_in[1];
  const float* V = (const float*)d_in[2];
  // d_in[3] = mask: causal tril, implemented analytically
  const float* Wq = (const float*)d_in[4];
  const float* bq = (const float*)d_in[5];
  const float* Wk = (const float*)d_in[6];
  const float* bk = (const float*)d_in[7];
  const float* Wv = (const float*)d_in[8];
  const float* bv = (const float*)d_in[9];
  const float* Wo = (const float*)d_in[10];
  const float* bo = (const float*)d_in[11];
  float* out = (float*)d_out;

  constexpr size_t BIG = (size_t)NB * SEQ * D_MODEL;  // 8388608
  constexpr size_t WN = (size_t)D_MODEL * D_MODEL;    // 1048576
  unsigned short* ws = (unsigned short*)d_ws;
  unsigned short* Qb = ws;                    // [0, BIG)
  unsigned short* Wob = ws + 3 * BIG + 3 * WN;
  unsigned short* qkv = Wob + WN;             // qb, kb, vTb consecutive
  unsigned short* qb = qkv;
  unsigned short* kb = qb + BIG;
  unsigned short* vTb = kb + BIG;
  unsigned short* ctx = Qb;  // Qb dead after the QKV GEMM

  dim3 blk(256);
  convert_all<<<dim3(3 * 4096 + 4 * 512), blk, 0, stream>>>(Q, Kin, V, Wq, Wk, Wv,
                                                            Wo, ws);
  qkv_gemm<<<dim3(D_MODEL / 128, NB * SEQ / 128, 3), blk, 0, stream>>>(ws, bq, bk,
                                                                       bv, qkv);
  attn_kernel<<<dim3(16, NB * NH), blk, 0, stream>>>(qb, kb, vTb, ctx);
  gemm_out<<<dim3(D_MODEL / 128, NB * SEQ / 128), blk, 0, stream>>>(ctx, Wob, bo,
                                                                    out);
}

// Round 5
// 378.992 us; speedup vs baseline: 1.5147x; 1.0340x over previous
//
#include <hip/hip_runtime.h>

#define DEV __device__ __forceinline__

typedef __attribute__((ext_vector_type(4))) float f32x4;
typedef __attribute__((ext_vector_type(8))) short s16x8;
typedef __attribute__((ext_vector_type(8))) __bf16 bf16x8;

static constexpr int D_MODEL = 1024;
static constexpr int SEQ = 2048;
static constexpr int NB = 4;
static constexpr int NH = 16;

DEV unsigned short f2bf(float f) {
  __bf16 h = (__bf16)f;  // RNE; compiler packs pairs into v_cvt_pk_bf16_f32
  return __builtin_bit_cast(unsigned short, h);
}

DEV float fexp2(float x) { return __builtin_amdgcn_exp2f(x); }

DEV s16x8 pack8(f32x4 a, f32x4 b) {
  bf16x8 r;
  r[0] = (__bf16)a[0]; r[1] = (__bf16)a[1]; r[2] = (__bf16)a[2]; r[3] = (__bf16)a[3];
  r[4] = (__bf16)b[0]; r[5] = (__bf16)b[1]; r[6] = (__bf16)b[2]; r[7] = (__bf16)b[3];
  return __builtin_bit_cast(s16x8, r);
}

DEV f32x4 MFMA(s16x8 a, s16x8 b, f32x4 c) {
  return __builtin_amdgcn_mfma_f32_16x16x32_bf16(
      __builtin_bit_cast(bf16x8, a), __builtin_bit_cast(bf16x8, b), c, 0, 0, 0);
}

typedef const __attribute__((address_space(1))) void gas_t;
typedef __attribute__((address_space(3))) void las_t;
DEV void gload16(const void* g, void* l) {
  __builtin_amdgcn_global_load_lds((gas_t*)(unsigned long long)g,
                                   (las_t*)(unsigned int)(unsigned long long)l,
                                   16, 0, 0);
}

// ---------------- convert fp32 -> bf16 (7 tensors) ----------------
__global__ __launch_bounds__(256) void convert_all(
    const float* __restrict__ Q, const float* __restrict__ K,
    const float* __restrict__ V, const float* __restrict__ Wq,
    const float* __restrict__ Wk, const float* __restrict__ Wv,
    const float* __restrict__ Wo, unsigned short* __restrict__ ws) {
  constexpr int BIG = NB * SEQ * D_MODEL;  // 8388608
  constexpr int WN = D_MODEL * D_MODEL;    // 1048576
  constexpr int BIGB = BIG / 8 / 256;      // 4096 blocks
  constexpr int WB = WN / 8 / 256;         // 512 blocks
  const int blk = blockIdx.x;
  const float* src;
  unsigned short* dst;
  int boff;
  if (blk < 3 * BIGB) {
    const int r = blk / BIGB;
    boff = blk - r * BIGB;
    src = (r == 0) ? Q : ((r == 1) ? K : V);
    dst = ws + (size_t)r * BIG;
  } else {
    const int r = (blk - 3 * BIGB) / WB;
    boff = (blk - 3 * BIGB) - r * WB;
    src = (r == 0) ? Wq : ((r == 1) ? Wk : ((r == 2) ? Wv : Wo));
    dst = ws + (size_t)3 * BIG + (size_t)r * WN;
  }
  const size_t idx = ((size_t)boff * 256 + threadIdx.x) * 8;
  f32x4 a = *(const f32x4*)(src + idx);
  f32x4 b = *(const f32x4*)(src + idx + 4);
  *(s16x8*)(dst + idx) = pack8(a, b);
}

// ---------------- fused QKV GEMM (grid.z selects q/k/v) ----------------
// C[m,n] = sum_k A[m,k]*W[n,k] + bias[n]
// z=0: q bf16 [BH][S][64] * 0.125*log2(e); z=1: k bf16 [BH][S][64];
// z=2: vT bf16 [BH][64][S]
__global__ __launch_bounds__(256) void qkv_gemm(const unsigned short* __restrict__ ws,
                                                const float* __restrict__ bq,
                                                const float* __restrict__ bk,
                                                const float* __restrict__ bv,
                                                unsigned short* __restrict__ outb) {
  constexpr int K = 1024, BK = 64;
  constexpr size_t BIG = (size_t)NB * SEQ * D_MODEL;
  constexpr size_t WN = (size_t)D_MODEL * D_MODEL;
  __shared__ __align__(16) unsigned char ldsA[2][128 * BK * 2];
  __shared__ __align__(16) unsigned char ldsB[2][128 * BK * 2];

  const int z = blockIdx.z;
  const unsigned short* Ap = ws + (size_t)z * BIG;
  const unsigned short* Wp = ws + 3 * BIG + (size_t)z * WN;
  const float* bias = (z == 0) ? bq : ((z == 1) ? bk : bv);
  unsigned short* outp = outb + (size_t)z * BIG;

  const int tid = threadIdx.x;
  const int wid = tid >> 6, lane = tid & 63;
  const int g16 = lane >> 4, l16 = lane & 15;
  const int m0 = blockIdx.y * 128;
  const int n0 = blockIdx.x * 128;
  const int wm = (wid >> 1) * 64, wn = (wid & 1) * 64;

  f32x4 acc[4][4];
#pragma unroll
  for (int a = 0; a < 4; ++a)
#pragma unroll
    for (int b = 0; b < 4; ++b) acc[a][b] = f32x4{0.f, 0.f, 0.f, 0.f};

  auto stage = [&](int buf, int kt) {
    const int k0 = kt * BK;
#pragma unroll
    for (int t = 0; t < 4; ++t) {
      const int seg = wid * 4 + t;
      const int cid = seg * 64 + lane;
      const int r = cid >> 3;
      const int c = ((cid & 7) ^ (r & 7)) * 8;
      gload16(Ap + (size_t)(m0 + r) * K + k0 + c, ldsA[buf] + seg * 1024);
      gload16(Wp + (size_t)(n0 + r) * K + k0 + c, ldsB[buf] + seg * 1024);
    }
  };

  auto compute = [&](int buf) {
#pragma unroll
    for (int ks = 0; ks < 2; ++ks) {
      const int kb2 = (ks * 32 + g16 * 8) * 2;
      s16x8 af[4], bfr[4];
#pragma unroll
      for (int mf = 0; mf < 4; ++mf) {
        const int row = wm + mf * 16 + l16;
        af[mf] = *(const s16x8*)(ldsA[buf] + ((row * 128 + kb2) ^ ((row & 7) << 4)));
      }
#pragma unroll
      for (int nf = 0; nf < 4; ++nf) {
        const int row = wn + nf * 16 + l16;
        bfr[nf] = *(const s16x8*)(ldsB[buf] + ((row * 128 + kb2) ^ ((row & 7) << 4)));
      }
#pragma unroll
      for (int mf = 0; mf < 4; ++mf)
#pragma unroll
        for (int nf = 0; nf < 4; ++nf)
          acc[mf][nf] = MFMA(af[mf], bfr[nf], acc[mf][nf]);
    }
  };

  stage(0, 0);
  __syncthreads();
  int buf = 0;
#pragma unroll 1
  for (int kt = 0; kt < K / BK; ++kt) {
    if (kt + 1 < K / BK) stage(buf ^ 1, kt + 1);
    compute(buf);
    __syncthreads();
    buf ^= 1;
  }

#pragma unroll
  for (int nf = 0; nf < 4; ++nf) {
    const int n = n0 + wn + nf * 16 + l16;
    const float bv_ = bias[n];
#pragma unroll
    for (int mf = 0; mf < 4; ++mf) {
#pragma unroll
      for (int i = 0; i < 4; ++i) {
        const int m = m0 + wm + mf * 16 + g16 * 4 + i;
        float v = acc[mf][nf][i] + bv_;
        if (z == 0) v *= 0.18033688011112042f;  // 0.125*log2(e)
        const int bh = (m >> 11) * NH + (n >> 6);
        if (z < 2) {
          outp[((size_t)bh * SEQ + (m & 2047)) * 64 + (n & 63)] = f2bf(v);
        } else {
          outp[((size_t)bh * 64 + (n & 63)) * SEQ + (m & 2047)] = f2bf(v);
        }
      }
    }
  }
}

// ---------------- output GEMM: fp32 out ----------------
__global__ __launch_bounds__(256) void gemm_out(const unsigned short* __restrict__ Ap,
                                                const unsigned short* __restrict__ Wp,
                                                const float* __restrict__ bias,
                                                float* __restrict__ outp) {
  constexpr int K = 1024, BK = 64;
  __shared__ __align__(16) unsigned char ldsA[2][128 * BK * 2];
  __shared__ __align__(16) unsigned char ldsB[2][128 * BK * 2];

  const int tid = threadIdx.x;
  const int wid = tid >> 6, lane = tid & 63;
  const int g16 = lane >> 4, l16 = lane & 15;
  const int m0 = blockIdx.y * 128;
  const int n0 = blockIdx.x * 128;
  const int wm = (wid >> 1) * 64, wn = (wid & 1) * 64;

  f32x4 acc[4][4];
#pragma unroll
  for (int a = 0; a < 4; ++a)
#pragma unroll
    for (int b = 0; b < 4; ++b) acc[a][b] = f32x4{0.f, 0.f, 0.f, 0.f};

  auto stage = [&](int buf, int kt) {
    const int k0 = kt * BK;
#pragma unroll
    for (int t = 0; t < 4; ++t) {
      const int seg = wid * 4 + t;
      const int cid = seg * 64 + lane;
      const int r = cid >> 3;
      const int c = ((cid & 7) ^ (r & 7)) * 8;
      gload16(Ap + (size_t)(m0 + r) * K + k0 + c, ldsA[buf] + seg * 1024);
      gload16(Wp + (size_t)(n0 + r) * K + k0 + c, ldsB[buf] + seg * 1024);
    }
  };

  auto compute = [&](int buf) {
#pragma unroll
    for (int ks = 0; ks < 2; ++ks) {
      const int kb2 = (ks * 32 + g16 * 8) * 2;
      s16x8 af[4], bfr[4];
#pragma unroll
      for (int mf = 0; mf < 4; ++mf) {
        const int row = wm + mf * 16 + l16;
        af[mf] = *(const s16x8*)(ldsA[buf] + ((row * 128 + kb2) ^ ((row & 7) << 4)));
      }
#pragma unroll
      for (int nf = 0; nf < 4; ++nf) {
        const int row = wn + nf * 16 + l16;
        bfr[nf] = *(const s16x8*)(ldsB[buf] + ((row * 128 + kb2) ^ ((row & 7) << 4)));
      }
#pragma unroll
      for (int mf = 0; mf < 4; ++mf)
#pragma unroll
        for (int nf = 0; nf < 4; ++nf)
          acc[mf][nf] = MFMA(af[mf], bfr[nf], acc[mf][nf]);
    }
  };

  stage(0, 0);
  __syncthreads();
  int buf = 0;
#pragma unroll 1
  for (int kt = 0; kt < K / BK; ++kt) {
    if (kt + 1 < K / BK) stage(buf ^ 1, kt + 1);
    compute(buf);
    __syncthreads();
    buf ^= 1;
  }

#pragma unroll
  for (int nf = 0; nf < 4; ++nf) {
    const int n = n0 + wn + nf * 16 + l16;
    const float bv_ = bias[n];
#pragma unroll
    for (int mf = 0; mf < 4; ++mf) {
#pragma unroll
      for (int i = 0; i < 4; ++i) {
        const int m = m0 + wm + mf * 16 + g16 * 4 + i;
        outp[(size_t)m * D_MODEL + n] = acc[mf][nf][i] + bv_;
      }
    }
  }
}

// ---------------- causal flash attention ----------------
// grid (16, B*H). Block jj handles q-tiles tA=31-jj and tB=jj (uniform 33 units).
// K MFMA rows permuted by F(jn,r)=32(jn&1)+8(r>>2)+4(jn>>1)+(r&3) so that the
// P matrix lands lane-local in the PV A-fragment layout (zero shuffles).
// LDS swizzle xi(r) = (r&3)|(((r>>3)&1)<<2) on both stage-source and read.
__global__ __launch_bounds__(256) void attn_kernel(
    const unsigned short* __restrict__ q, const unsigned short* __restrict__ k,
    const unsigned short* __restrict__ vT, unsigned short* __restrict__ ctx) {
  __shared__ __align__(16) unsigned char ldsK[2][64 * 64 * 2];
  __shared__ __align__(16) unsigned char ldsV[2][64 * 64 * 2];

  const int tid = threadIdx.x, wid = tid >> 6, lane = tid & 63;
  const int g16 = lane >> 4, l16 = lane & 15;
  const int bh = blockIdx.y;
  const int jj = blockIdx.x;
  const int tA = 31 - jj, tB = jj;
  const int qrA = tA * 64 + wid * 16, qrB = tB * 64 + wid * 16;
  const size_t qbase = (size_t)bh * SEQ;

  s16x8 qfA[2], qfB[2];
#pragma unroll
  for (int ks = 0; ks < 2; ++ks) {
    qfA[ks] = *(const s16x8*)(q + (qbase + qrA + l16) * 64 + ks * 32 + g16 * 8);
    qfB[ks] = *(const s16x8*)(q + (qbase + qrB + l16) * 64 + ks * 32 + g16 * 8);
  }

  float mA = -3.0e38f, lA = 0.f, mB = -3.0e38f, lB = 0.f;
  f32x4 oA[4], oB[4];
#pragma unroll
  for (int i = 0; i < 4; ++i) {
    oA[i] = f32x4{0.f, 0.f, 0.f, 0.f};
    oB[i] = f32x4{0.f, 0.f, 0.f, 0.f};
  }

  const int srcb = (lane & 48) + ((lane & 48) >> 2);  // lane (g, 4g) of own group

  // K-read lane base: row part 8*(l16>>2)+(l16&3); xi(F(jn,l16)) == l16&7
  const int kRowB = (8 * (l16 >> 2) + (l16 & 3)) * 128;
  // V-read: row = 16*jd + l16; xi = (l16&3)|((l16>>3)<<2)
  const int vRowB = l16 * 128;
  const int xiV = ((l16 & 3) | ((l16 >> 3) << 2)) << 4;
  const int xiK = (l16 & 7) << 4;

  auto stage = [&](int buf, int kt) {
    const int kv0 = kt * 64;
#pragma unroll
    for (int t = 0; t < 2; ++t) {
      const int seg = wid * 2 + t;
      const int cid = seg * 64 + lane;
      const int r = cid >> 3;
      const int xi = (r & 3) | (((r >> 3) & 1) << 2);
      const int c = ((cid & 7) ^ xi) * 8;
      gload16(k + (qbase + kv0 + r) * 64 + c, ldsK[buf] + seg * 1024);
      gload16(vT + ((size_t)bh * 64 + r) * SEQ + kv0 + c, ldsV[buf] + seg * 1024);
    }
  };

  // online softmax with defer-max; P lands lane-local for PV
  auto softmax = [&](f32x4* sc, float& mrun, float& lrun, f32x4* o, bool diag,
                     s16x8* pa) {
    if (diag) {
#pragma unroll
      for (int jn = 0; jn < 4; ++jn)
#pragma unroll
        for (int i = 0; i < 4; ++i) {
          const int kvp = 32 * (jn & 1) + 8 * g16 + 4 * (jn >> 1) + i;
          if (kvp > wid * 16 + l16) sc[jn][i] = -3.0e38f;
        }
    }
    // max-reduce as v_max3 chain: 16 elements -> max3 x7 + fmax x1
    float pm = fmaxf(fmaxf(sc[0][0], sc[0][1]), sc[0][2]);
    pm = fmaxf(fmaxf(pm, sc[0][3]), sc[1][0]);
    pm = fmaxf(fmaxf(pm, sc[1][1]), sc[1][2]);
    pm = fmaxf(fmaxf(pm, sc[1][3]), sc[2][0]);
    pm = fmaxf(fmaxf(pm, sc[2][1]), sc[2][2]);
    pm = fmaxf(fmaxf(pm, sc[2][3]), sc[3][0]);
    pm = fmaxf(fmaxf(pm, sc[3][1]), sc[3][2]);
    pm = fmaxf(pm, sc[3][3]);
    pm = fmaxf(pm, __shfl_xor(pm, 16, 64));
    pm = fmaxf(pm, __shfl_xor(pm, 32, 64));
    if (__any(pm > mrun + 8.0f)) {  // defer-max: rescale only on large growth
      const float mnew = fmaxf(mrun, pm);
      const float sca = fexp2(mrun - mnew);
      lrun *= sca;
#pragma unroll
      for (int i = 0; i < 4; ++i) {
        const float si = __shfl(sca, srcb + i, 64);
#pragma unroll
        for (int jd = 0; jd < 4; ++jd) o[jd][i] *= si;
      }
      mrun = mnew;
    }
    float tsum = 0.f;
#pragma unroll
    for (int jn = 0; jn < 4; ++jn) {
#pragma unroll
      for (int i = 0; i < 4; ++i) sc[jn][i] = fexp2(sc[jn][i] - mrun);
      tsum += (sc[jn][0] + sc[jn][1]) + (sc[jn][2] + sc[jn][3]);
    }
    tsum += __shfl_xor(tsum, 16, 64);
    tsum += __shfl_xor(tsum, 32, 64);
    lrun += tsum;
    // pa[ks] element e = P[q=l16][kv=32ks+8g16+e] = sc[2*(e>>2)+ks][e&3]
#pragma unroll
    for (int ks = 0; ks < 2; ++ks) {
      bf16x8 t;
      t[0] = (__bf16)sc[ks][0]; t[1] = (__bf16)sc[ks][1];
      t[2] = (__bf16)sc[ks][2]; t[3] = (__bf16)sc[ks][3];
      t[4] = (__bf16)sc[ks + 2][0]; t[5] = (__bf16)sc[ks + 2][1];
      t[6] = (__bf16)sc[ks + 2][2]; t[7] = (__bf16)sc[ks + 2][3];
      pa[ks] = __builtin_bit_cast(s16x8, t);
    }
  };

  stage(0, 0);
  __syncthreads();
  int buf = 0;
#pragma unroll 1
  for (int kt = 0; kt <= tA; ++kt) {
    if (kt < tA) stage(buf ^ 1, kt + 1);
    const bool doB = (kt <= tB);
    f32x4 scA[4], scB[4];
#pragma unroll
    for (int jn = 0; jn < 4; ++jn) {
      scA[jn] = f32x4{0.f, 0.f, 0.f, 0.f};
      scB[jn] = f32x4{0.f, 0.f, 0.f, 0.f};
    }
    __builtin_amdgcn_s_setprio(1);
#pragma unroll
    for (int ks = 0; ks < 2; ++ks) {
      const int kb = ((64 * ks + 16 * g16) ^ xiK) + kRowB;
#pragma unroll
      for (int jn = 0; jn < 4; ++jn) {
        // row F(jn,l16): imm offset 4096*(jn&1) + 512*(jn>>1)
        const int off = kb + 4096 * (jn & 1) + 512 * (jn >> 1);
        s16x8 kf = *(const s16x8*)(ldsK[buf] + off);
        scA[jn] = MFMA(kf, qfA[ks], scA[jn]);
        if (doB) scB[jn] = MFMA(kf, qfB[ks], scB[jn]);
      }
    }
    __builtin_amdgcn_s_setprio(0);
    s16x8 paA[2], paB[2];
    softmax(scA, mA, lA, oA, kt == tA, paA);
    if (doB) softmax(scB, mB, lB, oB, kt == tB, paB);
    __builtin_amdgcn_s_setprio(1);
#pragma unroll
    for (int ks = 0; ks < 2; ++ks) {
      const int vb = ((64 * ks + 16 * g16) ^ xiV) + vRowB;
#pragma unroll
      for (int jd = 0; jd < 4; ++jd) {
        s16x8 vf = *(const s16x8*)(ldsV[buf] + vb + 2048 * jd);
        oA[jd] = MFMA(paA[ks], vf, oA[jd]);
        if (doB) oB[jd] = MFMA(paB[ks], vf, oB[jd]);
      }
    }
    __builtin_amdgcn_s_setprio(0);
    __syncthreads();
    buf ^= 1;
  }

  const int b = bh >> 4, h = bh & 15;
  auto epi = [&](const f32x4* o, float lrun, int qr) {
#pragma unroll
    for (int i = 0; i < 4; ++i) {
      const float li = __builtin_amdgcn_rcpf(__shfl(lrun, srcb + i, 64));
      const int qi = qr + g16 * 4 + i;
      unsigned short* dst = ctx + ((size_t)(b * SEQ + qi)) * D_MODEL + h * 64;
#pragma unroll
      for (int jd = 0; jd < 4; ++jd) dst[jd * 16 + l16] = f2bf(o[jd][i] * li);
    }
  };
  epi(oA, lA, qrA);
  epi(oB, lB, qrB);
}

extern "C" void kernel_launch(void* const* d_in, const int* in_sizes, int n_in,
                              void* d_out, int out_size, void* d_ws, size_t ws_size,
                              hipStream_t stream) {
  const float* Q = (const float*)d_in[0];
  const float* Kin = (const float*)d_in[1];
  const float* V = (const float*)d_in[2];
  // d_in[3] = mask: causal tril, implemented analytically
  const float* Wq = (const float*)d_in[4];
  const float* bq = (const float*)d_in[5];
  const float* Wk = (const float*)d_in[6];
  const float* bk = (const float*)d_in[7];
  const float* Wv = (const float*)d_in[8];
  const float* bv = (const float*)d_in[9];
  const float* Wo = (const float*)d_in[10];
  const float* bo = (const float*)d_in[11];
  float* out = (float*)d_out;

  constexpr size_t BIG = (size_t)NB * SEQ * D_MODEL;  // 8388608
  constexpr size_t WN = (size_t)D_MODEL * D_MODEL;    // 1048576
  unsigned short* ws = (unsigned short*)d_ws;
  unsigned short* Qb = ws;                    // [0, BIG)
  unsigned short* Wob = ws + 3 * BIG + 3 * WN;
  unsigned short* qkv = Wob + WN;             // qb, kb, vTb consecutive
  unsigned short* qb = qkv;
  unsigned short* kb = qb + BIG;
  unsigned short* vTb = kb + BIG;
  unsigned short* ctx = Qb;  // Qb dead after the QKV GEMM

  dim3 blk(256);
  convert_all<<<dim3(3 * 4096 + 4 * 512), blk, 0, stream>>>(Q, Kin, V, Wq, Wk, Wv,
                                                            Wo, ws);
  qkv_gemm<<<dim3(D_MODEL / 128, NB * SEQ / 128, 3), blk, 0, stream>>>(ws, bq, bk,
                                                                       bv, qkv);
  attn_kernel<<<dim3(16, NB * NH), blk, 0, stream>>>(qb, kb, vTb, ctx);
  gemm_out<<<dim3(D_MODEL / 128, NB * SEQ / 128), blk, 0, stream>>>(ctx, Wob, bo,
                                                                    out);
}